// Round 4
// baseline (924.861 us; speedup 1.0000x reference)
//
#include <hip/hip_runtime.h>

// SparseAffinity_Propagate: CSPN-style 8-neighbor propagation, 24 iterations.
// B=8, H=W=768. Offsets (dy,dx): (-5,0)(-1,0)(0,5)(0,1)(5,0)(1,0)(0,-5)(0,-1)
//
// R0: fused form  result = sum_c (A*w_c) * prev[p+off_c] + Bias
// R1: w fp16 (16 B/px), bias fp32.
// R2: 4 px/thread, aligned 16B vectors.
// R3: batch->XCD partition (b = L&7): prev/next XCD-local.  948 -> 761 us.
// R4: w j-plane layout (dense 64B lines). 761 -> 748 (writes ideal; not the wall).
// R5: persistent cooperative kernel: FAILED (6.8 ms under rocprof). grid.sync
//     + device fences flush the non-coherent per-XCD L2s every iteration
//     (FETCH 90 MB/iter from HBM) and the barrier serializes. Also not
//     graph-capturable (timed run silently used the fallback). Removed.
// R6: (a) fuse precompute+step1 (kills the 94 MB w/bias write->read round
//     trip, -1 launch); (b) non-temporal hints on w/bias (11.8 MB/XCD, can
//     never fit L2 -> don't let them evict prev/next which DO fit: 4.7
//     MB/XCD). prev taps + next writes become L2-resident.

#define HH 768
#define WW 768
#define BATCH 8
#define PLANE (HH * WW)           // 589824
#define TOTAL (BATCH * PLANE)     // 4718592
#define NG (TOTAL / 4)            // 1179648 pixel-groups
#define NITER 24

#define DYS {-5, -1, 0, 0, 5, 1, 0, 0}
#define DXS {0, 0, 5, 1, 0, 0, -5, -1}

typedef _Float16 half8 __attribute__((ext_vector_type(8)));
typedef float f4 __attribute__((ext_vector_type(4)));

__device__ __forceinline__ f4 ldf4(const float* p) { return *(const f4*)p; }
// non-temporal (streaming) accessors for the L2-thrashing w/bias streams
__device__ __forceinline__ half8 ntl_h8(const half8* p) {
    return __builtin_nontemporal_load(p);
}
__device__ __forceinline__ f4 ntl_f4(const float* p) {
    return __builtin_nontemporal_load((const f4*)p);
}
__device__ __forceinline__ void nts_h8(half8* p, half8 v) {
    __builtin_nontemporal_store(v, p);
}
__device__ __forceinline__ void nts_f4(float* p, f4 v) {
    __builtin_nontemporal_store(v, (f4*)p);
}

// ---------------------------------------------------------------------------
// R6 fused kernel: precompute w/bias AND apply step 1 (prev = blur).
// Block = 192 threads = one row (4 px/thread). Grid (6144): b=L&7, y=L>>3.
// ---------------------------------------------------------------------------
__global__ __launch_bounds__(192) void fused_pre_step1_kernel(
    const float* __restrict__ g,       // (B,8,H,W)
    const float* __restrict__ blur,    // (B,1,H,W)
    const float* __restrict__ sparse,  // (B,1,H,W)
    half8* __restrict__ wout,          // 4 j-planes x NG half8
    float* __restrict__ bias,          // (B*H*W)
    float* __restrict__ next)          // step-1 output
{
    const int L  = blockIdx.x;
    const int b  = L & 7;              // XCD partition (round-robin dispatch)
    const int y  = L >> 3;
    const int x0 = 4 * threadIdx.x;
    const float* gb = g + (size_t)b * 8 * PLANE;
    const int rowb = y * WW;
    const int pidx = b * PLANE + rowb + x0;
    const int pg   = pidx >> 2;
    const float* pb = blur + (size_t)b * PLANE;   // prev = blur for step 1

    const bool interior = (x0 >= 8 && x0 <= 756);

    // ---------------- weights from guidance -------------------------------
    f4 wv[8];
    if (interior) {
        const f4 zero = (f4)0.f;
        wv[0] = (y >= 5)      ? ldf4(gb + 0 * PLANE + (y - 5) * WW + x0) : zero;
        wv[1] = (y >= 1)      ? ldf4(gb + 1 * PLANE + (y - 1) * WW + x0) : zero;
        wv[4] = (y <= HH - 6) ? ldf4(gb + 4 * PLANE + (y + 5) * WW + x0) : zero;
        wv[5] = (y <= HH - 2) ? ldf4(gb + 5 * PLANE + (y + 1) * WW + x0) : zero;
        {   // c=2, dx=+5
            f4 a  = ldf4(gb + 2 * PLANE + rowb + x0 + 4);
            f4 bq = ldf4(gb + 2 * PLANE + rowb + x0 + 8);
            wv[2] = f4{a[1], a[2], a[3], bq[0]};
        }
        {   // c=3, dx=+1
            f4 a  = ldf4(gb + 3 * PLANE + rowb + x0);
            f4 bq = ldf4(gb + 3 * PLANE + rowb + x0 + 4);
            wv[3] = f4{a[1], a[2], a[3], bq[0]};
        }
        {   // c=6, dx=-5
            f4 a  = ldf4(gb + 6 * PLANE + rowb + x0 - 8);
            f4 bq = ldf4(gb + 6 * PLANE + rowb + x0 - 4);
            wv[6] = f4{a[3], bq[0], bq[1], bq[2]};
        }
        {   // c=7, dx=-1
            f4 a  = ldf4(gb + 7 * PLANE + rowb + x0 - 4);
            f4 bq = ldf4(gb + 7 * PLANE + rowb + x0);
            wv[7] = f4{a[3], bq[0], bq[1], bq[2]};
        }
    } else {
        const int dy[8] = DYS;
        const int dx[8] = DXS;
#pragma unroll
        for (int c = 0; c < 8; ++c) {
#pragma unroll
            for (int j = 0; j < 4; ++j) {
                int yy = y + dy[c];
                int xx = x0 + j + dx[c];
                float v = 0.f;
                if (yy >= 0 && yy < HH && xx >= 0 && xx < WW)
                    v = gb[c * PLANE + yy * WW + xx];
                wv[c][j] = v;
            }
        }
    }

    // ---------------- normalize, quantize, store w/bias -------------------
    f4 raw = ldf4(blur + pidx);
    f4 sd  = ldf4(sparse + pidx);
    f4 bout;
    half8 hvs[4];                       // all indices compile-time below
#pragma unroll
    for (int j = 0; j < 4; ++j) {
        float abssum = 0.f;
#pragma unroll
        for (int c = 0; c < 8; ++c) abssum += fabsf(wv[c][j]);
        float inv = 1.f / fmaxf(abssum, 1e-6f);
        float gs = 0.f;
#pragma unroll
        for (int c = 0; c < 8; ++c) gs += wv[c][j] * inv;
        float s = sd[j];
        float m = (s > 0.f) ? 1.f : ((s < 0.f) ? -1.f : 0.f);
        float A = 1.f - m;
        bout[j] = (A * (1.f - gs) + m) * raw[j];
        float Ai = A * inv;
        half8 hv;
#pragma unroll
        for (int c = 0; c < 8; ++c) hv[c] = (_Float16)(Ai * wv[c][j]);
        hvs[j] = hv;
        nts_h8(&wout[(size_t)j * NG + pg], hv);   // streaming store (no L2)
    }
    nts_f4(bias + pidx, bout);

    // ---------------- apply step 1 with the fp16-rounded weights ----------
    f4 acc = bout;
    if (interior) {
        const f4 zero = (f4)0.f;
        f4 um5 = (y >= 5)      ? ldf4(pb + (y - 5) * WW + x0) : zero;
        f4 um1 = (y >= 1)      ? ldf4(pb + (y - 1) * WW + x0) : zero;
        f4 dp5 = (y <= HH - 6) ? ldf4(pb + (y + 5) * WW + x0) : zero;
        f4 dp1 = (y <= HH - 2) ? ldf4(pb + (y + 1) * WW + x0) : zero;
        f4 m2 = ldf4(pb + rowb + x0 - 8);
        f4 m1 = ldf4(pb + rowb + x0 - 4);
        f4 c0 = ldf4(pb + rowb + x0);
        f4 p1 = ldf4(pb + rowb + x0 + 4);
        f4 p2 = ldf4(pb + rowb + x0 + 8);
        f4 tm5 = f4{m2[3], m1[0], m1[1], m1[2]};
        f4 tm1 = f4{m1[3], c0[0], c0[1], c0[2]};
        f4 tp1 = f4{c0[1], c0[2], c0[3], p1[0]};
        f4 tp5 = f4{p1[1], p1[2], p1[3], p2[0]};

        f4 taps[8] = {um5, um1, tp5, tp1, dp5, dp1, tm5, tm1};
#pragma unroll
        for (int c = 0; c < 8; ++c) {
#pragma unroll
            for (int j = 0; j < 4; ++j)
                acc[j] = fmaf((float)hvs[j][c], taps[c][j], acc[j]);
        }
    } else {
        const int dy[8] = DYS;
        const int dx[8] = DXS;
#pragma unroll
        for (int j = 0; j < 4; ++j) {
#pragma unroll
            for (int c = 0; c < 8; ++c) {
                int yy = y + dy[c];
                int xx = x0 + j + dx[c];
                float n = 0.f;
                if (yy >= 0 && yy < HH && xx >= 0 && xx < WW)
                    n = pb[yy * WW + xx];
                acc[j] = fmaf((float)hvs[j][c], n, acc[j]);
            }
        }
    }
    *(f4*)(next + pidx) = acc;
}

// ---------------------------------------------------------------------------
// Propagation step (iterations 2..24): out = sum_c w_c * prev[p+off_c] + bias
// Block = 192 threads = one row (4 px/thread). Grid (6144): b=L&7, y=L>>3.
// w/bias loaded non-temporally (streaming); prev/next cached (L2-resident).
// ---------------------------------------------------------------------------
__global__ __launch_bounds__(192) void step_kernel(
    const half8* __restrict__ w,     // 4 j-planes x NG half8
    const float* __restrict__ bias,  // (B*H*W)
    const float* __restrict__ prev,  // (B,H,W)
    float* __restrict__ next)        // (B,H,W)
{
    const int L  = blockIdx.x;
    const int b  = L & 7;
    const int y  = L >> 3;
    const int x0 = 4 * threadIdx.x;
    const int rowb = y * WW;
    const int pidx = b * PLANE + rowb + x0;
    const int pg   = pidx >> 2;
    const float* pb = prev + b * PLANE;

    half8 hv0 = ntl_h8(&w[0 * (size_t)NG + pg]);
    half8 hv1 = ntl_h8(&w[1 * (size_t)NG + pg]);
    half8 hv2 = ntl_h8(&w[2 * (size_t)NG + pg]);
    half8 hv3 = ntl_h8(&w[3 * (size_t)NG + pg]);
    f4 acc = ntl_f4(bias + pidx);

    if (x0 >= 8 && x0 <= 756) {
        const f4 zero = (f4)0.f;
        f4 um5 = (y >= 5)      ? ldf4(pb + (y - 5) * WW + x0) : zero;
        f4 um1 = (y >= 1)      ? ldf4(pb + (y - 1) * WW + x0) : zero;
        f4 dp5 = (y <= HH - 6) ? ldf4(pb + (y + 5) * WW + x0) : zero;
        f4 dp1 = (y <= HH - 2) ? ldf4(pb + (y + 1) * WW + x0) : zero;
        f4 m2 = ldf4(pb + rowb + x0 - 8);
        f4 m1 = ldf4(pb + rowb + x0 - 4);
        f4 c0 = ldf4(pb + rowb + x0);
        f4 p1 = ldf4(pb + rowb + x0 + 4);
        f4 p2 = ldf4(pb + rowb + x0 + 8);
        f4 tm5 = f4{m2[3], m1[0], m1[1], m1[2]};
        f4 tm1 = f4{m1[3], c0[0], c0[1], c0[2]};
        f4 tp1 = f4{c0[1], c0[2], c0[3], p1[0]};
        f4 tp5 = f4{p1[1], p1[2], p1[3], p2[0]};

        acc[0] = fmaf((float)hv0[0], um5[0], acc[0]);
        acc[1] = fmaf((float)hv1[0], um5[1], acc[1]);
        acc[2] = fmaf((float)hv2[0], um5[2], acc[2]);
        acc[3] = fmaf((float)hv3[0], um5[3], acc[3]);
        acc[0] = fmaf((float)hv0[1], um1[0], acc[0]);
        acc[1] = fmaf((float)hv1[1], um1[1], acc[1]);
        acc[2] = fmaf((float)hv2[1], um1[2], acc[2]);
        acc[3] = fmaf((float)hv3[1], um1[3], acc[3]);
        acc[0] = fmaf((float)hv0[2], tp5[0], acc[0]);
        acc[1] = fmaf((float)hv1[2], tp5[1], acc[1]);
        acc[2] = fmaf((float)hv2[2], tp5[2], acc[2]);
        acc[3] = fmaf((float)hv3[2], tp5[3], acc[3]);
        acc[0] = fmaf((float)hv0[3], tp1[0], acc[0]);
        acc[1] = fmaf((float)hv1[3], tp1[1], acc[1]);
        acc[2] = fmaf((float)hv2[3], tp1[2], acc[2]);
        acc[3] = fmaf((float)hv3[3], tp1[3], acc[3]);
        acc[0] = fmaf((float)hv0[4], dp5[0], acc[0]);
        acc[1] = fmaf((float)hv1[4], dp5[1], acc[1]);
        acc[2] = fmaf((float)hv2[4], dp5[2], acc[2]);
        acc[3] = fmaf((float)hv3[4], dp5[3], acc[3]);
        acc[0] = fmaf((float)hv0[5], dp1[0], acc[0]);
        acc[1] = fmaf((float)hv1[5], dp1[1], acc[1]);
        acc[2] = fmaf((float)hv2[5], dp1[2], acc[2]);
        acc[3] = fmaf((float)hv3[5], dp1[3], acc[3]);
        acc[0] = fmaf((float)hv0[6], tm5[0], acc[0]);
        acc[1] = fmaf((float)hv1[6], tm5[1], acc[1]);
        acc[2] = fmaf((float)hv2[6], tm5[2], acc[2]);
        acc[3] = fmaf((float)hv3[6], tm5[3], acc[3]);
        acc[0] = fmaf((float)hv0[7], tm1[0], acc[0]);
        acc[1] = fmaf((float)hv1[7], tm1[1], acc[1]);
        acc[2] = fmaf((float)hv2[7], tm1[2], acc[2]);
        acc[3] = fmaf((float)hv3[7], tm1[3], acc[3]);
    } else {
        const int dy[8] = DYS;
        const int dx[8] = DXS;
        half8 hvs[4] = {hv0, hv1, hv2, hv3};
#pragma unroll
        for (int j = 0; j < 4; ++j) {
#pragma unroll
            for (int c = 0; c < 8; ++c) {
                int yy = y + dy[c];
                int xx = x0 + j + dx[c];
                float n = 0.f;
                if (yy >= 0 && yy < HH && xx >= 0 && xx < WW)
                    n = pb[yy * WW + xx];
                acc[j] = fmaf((float)hvs[j][c], n, acc[j]);
            }
        }
    }
    *(f4*)(next + pidx) = acc;
}

// ---------------------------------------------------------------------------
// Fallback step (small ws): recompute weights/bias from inputs every step.
// ---------------------------------------------------------------------------
__global__ __launch_bounds__(256) void step_recompute_kernel(
    const float* __restrict__ g,
    const float* __restrict__ blur,
    const float* __restrict__ sparse,
    const float* __restrict__ prev,
    float* __restrict__ next)
{
    const int dy[8] = DYS;
    const int dx[8] = DXS;
    int x = blockIdx.x * blockDim.x + threadIdx.x;
    int y = blockIdx.y;
    int b = blockIdx.z;
    if (x >= WW) return;

    const float* gb = g + (size_t)b * 8 * PLANE;
    float w[8];
    float abssum = 0.f;
#pragma unroll
    for (int c = 0; c < 8; ++c) {
        int yy = y + dy[c];
        int xx = x + dx[c];
        float v = 0.f;
        if (yy >= 0 && yy < HH && xx >= 0 && xx < WW)
            v = gb[c * PLANE + yy * WW + xx];
        w[c] = v;
        abssum += fabsf(v);
    }
    float inv = 1.f / fmaxf(abssum, 1e-6f);
    float gs = 0.f;
#pragma unroll
    for (int c = 0; c < 8; ++c) {
        w[c] *= inv;
        gs += w[c];
    }
    int pidx = b * PLANE + y * WW + x;
    float sd = sparse[pidx];
    float m = (sd > 0.f) ? 1.f : ((sd < 0.f) ? -1.f : 0.f);
    float A = 1.f - m;
    float raw = blur[pidx];

    const float* pb = prev + b * PLANE;
    float acc = 0.f;
#pragma unroll
    for (int c = 0; c < 8; ++c) {
        int yy = y + dy[c];
        int xx = x + dx[c];
        float n = 0.f;
        if (yy >= 0 && yy < HH && xx >= 0 && xx < WW)
            n = pb[yy * WW + xx];
        acc = fmaf(A * w[c], n, acc);
    }
    next[pidx] = acc + (A * (1.f - gs) + m) * raw;
}

// ---------------------------------------------------------------------------
extern "C" void kernel_launch(void* const* d_in, const int* in_sizes, int n_in,
                              void* d_out, int out_size, void* d_ws, size_t ws_size,
                              hipStream_t stream) {
    const float* g      = (const float*)d_in[0];  // guidance (B,8,H,W)
    const float* blur   = (const float*)d_in[1];  // blur_depth (B,1,H,W)
    const float* sparse = (const float*)d_in[2];  // sparse_depth (B,1,H,W)
    float* out = (float*)d_out;

    dim3 blockStep(192, 1, 1);
    dim3 gridStep(HH * BATCH, 1, 1); // 6144 linear blocks, b=L&7, y=L>>3

    // fast path: fp16 j-plane weights (16 B/px) + fp32 bias + ping buffer
    const size_t need_fast = (size_t)TOTAL * 16 + (size_t)TOTAL * 4 * 2;

    if (ws_size >= need_fast) {
        half8* w    = (half8*)d_ws;                       // 4*NG x 16 B
        float* bias = (float*)((char*)d_ws + (size_t)TOTAL * 16);
        float* r0   = bias + TOTAL;

        // it = 0: precompute + step 1 fused; writes r0
        fused_pre_step1_kernel<<<gridStep, blockStep, 0, stream>>>(
            g, blur, sparse, w, bias, r0);

        const float* prev = r0;
        for (int it = 1; it < NITER; ++it) {
            float* nxt = (it % 2 == 0) ? r0 : out;  // it=23 -> out
            step_kernel<<<gridStep, blockStep, 0, stream>>>(w, bias, prev, nxt);
            prev = nxt;
        }
    } else {
        // Fallback: only one ping buffer in ws; recompute weights each step.
        dim3 block2(256, 1, 1);
        dim3 grid2(WW / 256, HH, BATCH);
        float* r0 = (float*)d_ws;
        const float* prev = blur;
        for (int it = 0; it < NITER; ++it) {
            float* nxt = (it % 2 == 0) ? r0 : out;
            step_recompute_kernel<<<grid2, block2, 0, stream>>>(g, blur, sparse,
                                                                prev, nxt);
            prev = nxt;
        }
    }
}

// Round 5
// 670.236 us; speedup vs baseline: 1.3799x; 1.3799x over previous
//
#include <hip/hip_runtime.h>

// SparseAffinity_Propagate: CSPN-style 8-neighbor propagation, 24 iterations.
// B=8, H=W=768. Offsets (dy,dx): (-5,0)(-1,0)(0,5)(0,1)(5,0)(1,0)(0,-5)(0,-1)
//
// R0: fused form  result = sum_c (A*w_c) * prev[p+off_c] + Bias
// R1: w fp16 (16 B/px), bias fp32.   R2: 4 px/thread, aligned 16B vectors.
// R3: batch->XCD partition (b = L&7).  948 -> 761 us.
// R4: w j-plane layout (dense 64B lines). 761 -> 748.
// R5: persistent cooperative kernel: FAILED (grid.sync flushes non-coherent
//     per-XCD L2s; 6.8 ms under rocprof; not graph-capturable). Removed.
// R6: precompute+step1 fusion WON (~13 us) but NT hints on w/bias REGRESSED
//     steps 27.3 -> 35.6 us/step (partial L2 hits on w/bias were worth more
//     than the prev eviction they cause). NT reverted here.
// R7: DOUBLE-STEP kernel. Steps are byte-bound at ~4.8 TB/s beyond-L2 and
//     w+bias (94 MB) dominates. Compute 2 steps per w/bias read: block owns
//     a 24x384 tile; phase 1 computes the step-A intermediate for tile+halo
//     (34x400, fp32) into LDS (53 KB); phase 2 applies step B from LDS with
//     core w/bias HELD IN REGISTERS (3 slots/thread @768 threads). Per-px
//     traffic 28 -> 20.4 B/step. FMA-identical numerics (fp32 intermediate).

#define HH 768
#define WW 768
#define BATCH 8
#define PLANE (HH * WW)           // 589824
#define TOTAL (BATCH * PLANE)     // 4718592
#define NG (TOTAL / 4)            // 1179648 pixel-groups
#define NITER 24

// double-step geometry
#define R24 24                    // core rows per block
#define XW 384                    // core cols per block (2 x-halves)
#define LROWS 34                  // R24 + 10 halo rows
#define XGRP 100                  // phase-1 f4-groups per row ([-8, +392))
#define CGRP 96                   // core f4-groups per row
#define LCOLS 400                 // floats per LDS row (XGRP*4)
#define DTH 768                   // threads in double-step block
#define CORE_ITEMS (R24 * CGRP)   // 2304 = 3 * 768 (exact!)
#define P1_ITEMS  (LROWS * XGRP)  // 3400
#define HALO_ITEMS (P1_ITEMS - CORE_ITEMS)  // 1096 = 768 + 328

#define DYS {-5, -1, 0, 0, 5, 1, 0, 0}
#define DXS {0, 0, 5, 1, 0, 0, -5, -1}

typedef _Float16 half8 __attribute__((ext_vector_type(8)));
typedef float f4 __attribute__((ext_vector_type(4)));

__device__ __forceinline__ f4 ldf4(const float* p) { return *(const f4*)p; }

// ---------------------------------------------------------------------------
// One full propagation step at pixel-group (b, y, x0), reading prev from
// global. Returns the f4 result; outputs the loaded w (4x half8) and bias.
// ---------------------------------------------------------------------------
__device__ __forceinline__ f4 step_at(
    const half8* __restrict__ w, const float* __restrict__ bias,
    const float* __restrict__ pb, int b, int y, int x0,
    half8 hv[4], f4* bsave)
{
    const int rowb = y * WW;
    const int pidx = b * PLANE + rowb + x0;
    const int pg   = pidx >> 2;
    hv[0] = w[0 * (size_t)NG + pg];
    hv[1] = w[1 * (size_t)NG + pg];
    hv[2] = w[2 * (size_t)NG + pg];
    hv[3] = w[3 * (size_t)NG + pg];
    f4 acc = ldf4(bias + pidx);
    *bsave = acc;

    if (x0 >= 8 && x0 <= 756) {
        const f4 zero = (f4)0.f;
        f4 um5 = (y >= 5)      ? ldf4(pb + (y - 5) * WW + x0) : zero;
        f4 um1 = (y >= 1)      ? ldf4(pb + (y - 1) * WW + x0) : zero;
        f4 dp5 = (y <= HH - 6) ? ldf4(pb + (y + 5) * WW + x0) : zero;
        f4 dp1 = (y <= HH - 2) ? ldf4(pb + (y + 1) * WW + x0) : zero;
        f4 m2 = ldf4(pb + rowb + x0 - 8);
        f4 m1 = ldf4(pb + rowb + x0 - 4);
        f4 c0 = ldf4(pb + rowb + x0);
        f4 p1 = ldf4(pb + rowb + x0 + 4);
        f4 p2 = ldf4(pb + rowb + x0 + 8);
        f4 tm5 = f4{m2[3], m1[0], m1[1], m1[2]};   // dx=-5
        f4 tm1 = f4{m1[3], c0[0], c0[1], c0[2]};   // dx=-1
        f4 tp1 = f4{c0[1], c0[2], c0[3], p1[0]};   // dx=+1
        f4 tp5 = f4{p1[1], p1[2], p1[3], p2[0]};   // dx=+5

        f4 taps[8] = {um5, um1, tp5, tp1, dp5, dp1, tm5, tm1};
#pragma unroll
        for (int c = 0; c < 8; ++c) {
#pragma unroll
            for (int j = 0; j < 4; ++j)
                acc[j] = fmaf((float)hv[j][c], taps[c][j], acc[j]);
        }
    } else {
        const int dy[8] = DYS;
        const int dx[8] = DXS;
#pragma unroll
        for (int j = 0; j < 4; ++j) {
#pragma unroll
            for (int c = 0; c < 8; ++c) {
                int yy = y + dy[c];
                int xx = x0 + j + dx[c];
                float n = 0.f;
                if (yy >= 0 && yy < HH && xx >= 0 && xx < WW)
                    n = pb[yy * WW + xx];
                acc[j] = fmaf((float)hv[j][c], n, acc[j]);
            }
        }
    }
    return acc;
}

// ---------------------------------------------------------------------------
// R7 double-step: two propagation steps, one w/bias read (+halo).
// Grid 512 = 32 bands x 2 x-halves x 8 batches; b = L&7 (XCD partition).
// Block 768 threads. LDS: u[34][400] fp32 = 53.1 KB.
// ---------------------------------------------------------------------------
__global__ __launch_bounds__(DTH, 3) void double_step_kernel(
    const half8* __restrict__ w,     // 4 j-planes x NG half8
    const float* __restrict__ bias,  // (B*H*W)
    const float* __restrict__ prev,  // (B,H,W)
    float* __restrict__ next)        // (B,H,W), advanced by TWO steps
{
    __shared__ float u[LROWS * LCOLS];

    const int L    = blockIdx.x;
    const int b    = L & 7;
    const int rem  = L >> 3;        // 0..63
    const int band = rem >> 1;      // 0..31
    const int xs   = (rem & 1) * XW;
    const int y0   = band * R24;
    const int t    = threadIdx.x;
    const float* pb = prev + (size_t)b * PLANE;

    half8 hw[3][4];   // held core weights (compile-time indexed)
    f4    hb[3];      // held core bias

    // ---------------- phase 1: intermediate u for tile+halo ---------------
    // core items first (k=0..2: item = k*768 + t), same order as phase 2.
#pragma unroll
    for (int k = 0; k < 3; ++k) {
        const int item = k * DTH + t;
        const int r    = item / CGRP;
        const int gxc  = item - r * CGRP;
        const int y    = y0 + r;              // always in [0,768)
        const int x0   = xs + 4 * gxc;        // always in [0,768)
        const int ly   = r + 5;
        const int lx   = 4 * gxc + 8;
        f4 uo = step_at(w, bias, pb, b, y, x0, hw[k], &hb[k]);
        *(f4*)&u[ly * LCOLS + lx] = uo;
    }
    // halo items: rows {0..4, 29..33} full width, + edge cols of core rows.
#pragma unroll
    for (int kh = 0; kh < 2; ++kh) {
        const int h = kh * DTH + t;
        if (h < HALO_ITEMS) {
            int ly, gx;
            if (h < 10 * XGRP) {              // 1000 items: halo rows
                const int rr = h / XGRP;      // 0..9
                ly = (rr < 5) ? rr : rr + R24;
                gx = h - rr * XGRP;
            } else {                          // 96 items: edge cols
                const int e = h - 10 * XGRP;  // 0..95
                ly = 5 + (e >> 2);
                const int q = e & 3;
                gx = (q < 2) ? q : 96 + q;    // {0,1,98,99}
            }
            const int y   = y0 - 5 + ly;
            const int x0i = xs - 8 + 4 * gx;
            f4 uo = (f4)0.f;
            if ((unsigned)y < HH && (unsigned)x0i < WW) {
                half8 hd[4]; f4 bd;
                uo = step_at(w, bias, pb, b, y, x0i, hd, &bd);
            }
            *(f4*)&u[ly * LCOLS + 4 * gx] = uo;
        }
    }

    __syncthreads();

    // ---------------- phase 2: step B from LDS, w/bias from registers -----
    // No guards needed: out-of-image taps read zeroed LDS cells.
#pragma unroll
    for (int k = 0; k < 3; ++k) {
        const int item = k * DTH + t;
        const int r    = item / CGRP;
        const int gxc  = item - r * CGRP;
        const int y    = y0 + r;
        const int x0   = xs + 4 * gxc;
        const int ly   = r + 5;
        const int lx   = 4 * gxc + 8;
        const float* ur = &u[ly * LCOLS];

        f4 um5 = *(const f4*)&u[(ly - 5) * LCOLS + lx];
        f4 um1 = *(const f4*)&u[(ly - 1) * LCOLS + lx];
        f4 dp5 = *(const f4*)&u[(ly + 5) * LCOLS + lx];
        f4 dp1 = *(const f4*)&u[(ly + 1) * LCOLS + lx];
        f4 m2 = *(const f4*)&ur[lx - 8];
        f4 m1 = *(const f4*)&ur[lx - 4];
        f4 c0 = *(const f4*)&ur[lx];
        f4 p1 = *(const f4*)&ur[lx + 4];
        f4 p2 = *(const f4*)&ur[lx + 8];
        f4 tm5 = f4{m2[3], m1[0], m1[1], m1[2]};
        f4 tm1 = f4{m1[3], c0[0], c0[1], c0[2]};
        f4 tp1 = f4{c0[1], c0[2], c0[3], p1[0]};
        f4 tp5 = f4{p1[1], p1[2], p1[3], p2[0]};

        f4 acc = hb[k];
        f4 taps[8] = {um5, um1, tp5, tp1, dp5, dp1, tm5, tm1};
#pragma unroll
        for (int c = 0; c < 8; ++c) {
#pragma unroll
            for (int j = 0; j < 4; ++j)
                acc[j] = fmaf((float)hw[k][j][c], taps[c][j], acc[j]);
        }
        *(f4*)(next + b * PLANE + y * WW + x0) = acc;
    }
}

// ---------------------------------------------------------------------------
// Fused precompute + step 1 (prev = blur). Plain (cached) stores — NT reverted.
// Block 192 = one row (4 px/thread). Grid 6144: b=L&7, y=L>>3.
// ---------------------------------------------------------------------------
__global__ __launch_bounds__(192) void fused_pre_step1_kernel(
    const float* __restrict__ g,
    const float* __restrict__ blur,
    const float* __restrict__ sparse,
    half8* __restrict__ wout,          // 4 j-planes x NG half8
    float* __restrict__ bias,
    float* __restrict__ next)
{
    const int L  = blockIdx.x;
    const int b  = L & 7;
    const int y  = L >> 3;
    const int x0 = 4 * threadIdx.x;
    const float* gb = g + (size_t)b * 8 * PLANE;
    const int rowb = y * WW;
    const int pidx = b * PLANE + rowb + x0;
    const int pg   = pidx >> 2;
    const float* pb = blur + (size_t)b * PLANE;

    const bool interior = (x0 >= 8 && x0 <= 756);

    f4 wv[8];
    if (interior) {
        const f4 zero = (f4)0.f;
        wv[0] = (y >= 5)      ? ldf4(gb + 0 * PLANE + (y - 5) * WW + x0) : zero;
        wv[1] = (y >= 1)      ? ldf4(gb + 1 * PLANE + (y - 1) * WW + x0) : zero;
        wv[4] = (y <= HH - 6) ? ldf4(gb + 4 * PLANE + (y + 5) * WW + x0) : zero;
        wv[5] = (y <= HH - 2) ? ldf4(gb + 5 * PLANE + (y + 1) * WW + x0) : zero;
        {   f4 a  = ldf4(gb + 2 * PLANE + rowb + x0 + 4);
            f4 bq = ldf4(gb + 2 * PLANE + rowb + x0 + 8);
            wv[2] = f4{a[1], a[2], a[3], bq[0]}; }
        {   f4 a  = ldf4(gb + 3 * PLANE + rowb + x0);
            f4 bq = ldf4(gb + 3 * PLANE + rowb + x0 + 4);
            wv[3] = f4{a[1], a[2], a[3], bq[0]}; }
        {   f4 a  = ldf4(gb + 6 * PLANE + rowb + x0 - 8);
            f4 bq = ldf4(gb + 6 * PLANE + rowb + x0 - 4);
            wv[6] = f4{a[3], bq[0], bq[1], bq[2]}; }
        {   f4 a  = ldf4(gb + 7 * PLANE + rowb + x0 - 4);
            f4 bq = ldf4(gb + 7 * PLANE + rowb + x0);
            wv[7] = f4{a[3], bq[0], bq[1], bq[2]}; }
    } else {
        const int dy[8] = DYS;
        const int dx[8] = DXS;
#pragma unroll
        for (int c = 0; c < 8; ++c) {
#pragma unroll
            for (int j = 0; j < 4; ++j) {
                int yy = y + dy[c];
                int xx = x0 + j + dx[c];
                float v = 0.f;
                if (yy >= 0 && yy < HH && xx >= 0 && xx < WW)
                    v = gb[c * PLANE + yy * WW + xx];
                wv[c][j] = v;
            }
        }
    }

    f4 raw = ldf4(blur + pidx);
    f4 sd  = ldf4(sparse + pidx);
    f4 bout;
    half8 hvs[4];
#pragma unroll
    for (int j = 0; j < 4; ++j) {
        float abssum = 0.f;
#pragma unroll
        for (int c = 0; c < 8; ++c) abssum += fabsf(wv[c][j]);
        float inv = 1.f / fmaxf(abssum, 1e-6f);
        float gs = 0.f;
#pragma unroll
        for (int c = 0; c < 8; ++c) gs += wv[c][j] * inv;
        float s = sd[j];
        float m = (s > 0.f) ? 1.f : ((s < 0.f) ? -1.f : 0.f);
        float A = 1.f - m;
        bout[j] = (A * (1.f - gs) + m) * raw[j];
        float Ai = A * inv;
        half8 hv;
#pragma unroll
        for (int c = 0; c < 8; ++c) hv[c] = (_Float16)(Ai * wv[c][j]);
        hvs[j] = hv;
        wout[(size_t)j * NG + pg] = hv;
    }
    *(f4*)(bias + pidx) = bout;

    // apply step 1 with the fp16-rounded weights
    f4 acc = bout;
    if (interior) {
        const f4 zero = (f4)0.f;
        f4 um5 = (y >= 5)      ? ldf4(pb + (y - 5) * WW + x0) : zero;
        f4 um1 = (y >= 1)      ? ldf4(pb + (y - 1) * WW + x0) : zero;
        f4 dp5 = (y <= HH - 6) ? ldf4(pb + (y + 5) * WW + x0) : zero;
        f4 dp1 = (y <= HH - 2) ? ldf4(pb + (y + 1) * WW + x0) : zero;
        f4 m2 = ldf4(pb + rowb + x0 - 8);
        f4 m1 = ldf4(pb + rowb + x0 - 4);
        f4 c0 = ldf4(pb + rowb + x0);
        f4 p1 = ldf4(pb + rowb + x0 + 4);
        f4 p2 = ldf4(pb + rowb + x0 + 8);
        f4 tm5 = f4{m2[3], m1[0], m1[1], m1[2]};
        f4 tm1 = f4{m1[3], c0[0], c0[1], c0[2]};
        f4 tp1 = f4{c0[1], c0[2], c0[3], p1[0]};
        f4 tp5 = f4{p1[1], p1[2], p1[3], p2[0]};

        f4 taps[8] = {um5, um1, tp5, tp1, dp5, dp1, tm5, tm1};
#pragma unroll
        for (int c = 0; c < 8; ++c) {
#pragma unroll
            for (int j = 0; j < 4; ++j)
                acc[j] = fmaf((float)hvs[j][c], taps[c][j], acc[j]);
        }
    } else {
        const int dy[8] = DYS;
        const int dx[8] = DXS;
#pragma unroll
        for (int j = 0; j < 4; ++j) {
#pragma unroll
            for (int c = 0; c < 8; ++c) {
                int yy = y + dy[c];
                int xx = x0 + j + dx[c];
                float n = 0.f;
                if (yy >= 0 && yy < HH && xx >= 0 && xx < WW)
                    n = pb[yy * WW + xx];
                acc[j] = fmaf((float)hvs[j][c], n, acc[j]);
            }
        }
    }
    *(f4*)(next + pidx) = acc;
}

// ---------------------------------------------------------------------------
// Single propagation step (plain cached loads — NT reverted).
// Block 192 = one row. Grid 6144: b=L&7, y=L>>3.
// ---------------------------------------------------------------------------
__global__ __launch_bounds__(192) void step_kernel(
    const half8* __restrict__ w,
    const float* __restrict__ bias,
    const float* __restrict__ prev,
    float* __restrict__ next)
{
    const int L  = blockIdx.x;
    const int b  = L & 7;
    const int y  = L >> 3;
    const int x0 = 4 * threadIdx.x;
    const float* pb = prev + (size_t)b * PLANE;
    half8 hv[4]; f4 bd;
    f4 acc = step_at(w, bias, pb, b, y, x0, hv, &bd);
    *(f4*)(next + b * PLANE + y * WW + x0) = acc;
}

// ---------------------------------------------------------------------------
// Fallback step (small ws): recompute weights/bias from inputs every step.
// ---------------------------------------------------------------------------
__global__ __launch_bounds__(256) void step_recompute_kernel(
    const float* __restrict__ g,
    const float* __restrict__ blur,
    const float* __restrict__ sparse,
    const float* __restrict__ prev,
    float* __restrict__ next)
{
    const int dy[8] = DYS;
    const int dx[8] = DXS;
    int x = blockIdx.x * blockDim.x + threadIdx.x;
    int y = blockIdx.y;
    int b = blockIdx.z;
    if (x >= WW) return;

    const float* gb = g + (size_t)b * 8 * PLANE;
    float w[8];
    float abssum = 0.f;
#pragma unroll
    for (int c = 0; c < 8; ++c) {
        int yy = y + dy[c];
        int xx = x + dx[c];
        float v = 0.f;
        if (yy >= 0 && yy < HH && xx >= 0 && xx < WW)
            v = gb[c * PLANE + yy * WW + xx];
        w[c] = v;
        abssum += fabsf(v);
    }
    float inv = 1.f / fmaxf(abssum, 1e-6f);
    float gs = 0.f;
#pragma unroll
    for (int c = 0; c < 8; ++c) {
        w[c] *= inv;
        gs += w[c];
    }
    int pidx = b * PLANE + y * WW + x;
    float sd = sparse[pidx];
    float m = (sd > 0.f) ? 1.f : ((sd < 0.f) ? -1.f : 0.f);
    float A = 1.f - m;
    float raw = blur[pidx];

    const float* pb = prev + b * PLANE;
    float acc = 0.f;
#pragma unroll
    for (int c = 0; c < 8; ++c) {
        int yy = y + dy[c];
        int xx = x + dx[c];
        float n = 0.f;
        if (yy >= 0 && yy < HH && xx >= 0 && xx < WW)
            n = pb[yy * WW + xx];
        acc = fmaf(A * w[c], n, acc);
    }
    next[pidx] = acc + (A * (1.f - gs) + m) * raw;
}

// ---------------------------------------------------------------------------
extern "C" void kernel_launch(void* const* d_in, const int* in_sizes, int n_in,
                              void* d_out, int out_size, void* d_ws, size_t ws_size,
                              hipStream_t stream) {
    const float* g      = (const float*)d_in[0];
    const float* blur   = (const float*)d_in[1];
    const float* sparse = (const float*)d_in[2];
    float* out = (float*)d_out;

    dim3 blockRow(192, 1, 1);
    dim3 gridRow(HH * BATCH, 1, 1);   // 6144: b=L&7, y=L>>3

    const size_t need_ds   = (size_t)TOTAL * 16 + (size_t)TOTAL * 4 * 3;  // w+bias+r0+r1
    const size_t need_fast = (size_t)TOTAL * 16 + (size_t)TOTAL * 4 * 2;  // w+bias+r0

    if (ws_size >= need_ds) {
        // R7 double-step path: fused(s1) + 11 doubles (s2..s23) + single(s24)
        half8* w    = (half8*)d_ws;
        float* bias = (float*)((char*)d_ws + (size_t)TOTAL * 16);
        float* r0   = bias + TOTAL;
        float* r1   = r0 + TOTAL;

        fused_pre_step1_kernel<<<gridRow, blockRow, 0, stream>>>(
            g, blur, sparse, w, bias, r0);

        float* pv = r0;
        float* nx = r1;
        for (int d = 0; d < 11; ++d) {
            double_step_kernel<<<dim3(512), dim3(DTH), 0, stream>>>(
                w, bias, pv, nx);
            float* tmp = pv; pv = nx; nx = tmp;
        }
        // after 11 doubles: s23 in pv (= r1). Final single step -> out.
        step_kernel<<<gridRow, blockRow, 0, stream>>>(w, bias, pv, out);
    } else if (ws_size >= need_fast) {
        // R6-minus-NT path: fused(s1) + 23 singles (pong = out)
        half8* w    = (half8*)d_ws;
        float* bias = (float*)((char*)d_ws + (size_t)TOTAL * 16);
        float* r0   = bias + TOTAL;

        fused_pre_step1_kernel<<<gridRow, blockRow, 0, stream>>>(
            g, blur, sparse, w, bias, r0);

        const float* prev = r0;
        for (int it = 1; it < NITER; ++it) {
            float* nxt = (it % 2 == 1) ? out : r0;  // it=23 (odd) -> out
            step_kernel<<<gridRow, blockRow, 0, stream>>>(w, bias, prev, nxt);
            prev = nxt;
        }
    } else {
        dim3 block2(256, 1, 1);
        dim3 grid2(WW / 256, HH, BATCH);
        float* r0 = (float*)d_ws;
        const float* prev = blur;
        for (int it = 0; it < NITER; ++it) {
            float* nxt = (it % 2 == 0) ? r0 : out;
            step_recompute_kernel<<<grid2, block2, 0, stream>>>(g, blur, sparse,
                                                                prev, nxt);
            prev = nxt;
        }
    }
}